// Round 15
// baseline (275.804 us; speedup 1.0000x reference)
//
#include <hip/hip_runtime.h>
#include <hip/hip_bf16.h>

// ---------------------------------------------------------------------------
// Recommender pipeline.
//  K1 prep   : detect bf16 inline (per-block, block0 publishes ws[0]);
//              weights -> ws; K-PACKED f32 (news/mlp); Wanc/Waw1 split-bf16.
//  K_fused   : blocks 0-439 = NEWS role (titles MLP, 8 rows, 256thr);
//              blocks 440+  = ANCHOR role (R12/R14 fused gather+MFMA).
//              News is independent of anchor -> hides under the anchor
//              phase's memory-bound slack. LDS aliased via one 34KB arena;
//              launch_bounds(256,4) -> 4 blocks/CU (duty-cycle up).
//  K5 mlp    : elu(elu([news_e,AE]@Wm1^T+b)@Wm2^T+b)          [3520,128]
//  K6 score  : user mean + dot                                 [64,5]
//  All accumulation chains byte-identical to R12/R14 -> absmax 0.0.
// ---------------------------------------------------------------------------

#define B_ 64
#define S_ 5
#define UC_ 50
#define A_ 20
#define NCAND 320
#define NCLK 3200
#define NNEWS 3520
#define NANCH 70400
#define NEWSBLK 440   // NNEWS/8

// ws layout (float indices)
static constexpr long OFF_WNC1P = 64;        // [192][128][4] f32
static constexpr long OFF_BNC1  = 98368;
static constexpr long OFF_WNC2P = 98496;     // [32][128][4] f32
static constexpr long OFF_BNC2  = 114880;
static constexpr long OFF_WANCP = 115008;    // [8kt][128n][32k] bf16 hi + lo (65536 ushort)
static constexpr long OFF_BANC  = 147776;
static constexpr long OFF_WAW1P = 147904;    // [4kt][128n][32k] bf16 hi + lo (32768 ushort)
static constexpr long OFF_BAW1  = 164288;
static constexpr long OFF_WAW2  = 164416;    // [128]
static constexpr long OFF_BAW2  = 164544;    // [1]
static constexpr long OFF_WM1P  = 164548;    // [64][128][4] f32
static constexpr long OFF_BM1   = 197316;
static constexpr long OFF_WM2P  = 197444;    // [32][128][4] f32
static constexpr long OFF_BM2   = 213828;
static constexpr long OFF_REL   = 213956;    // [100][128] f32
static constexpr long OFF_AE    = 226756;    // [3520][128] f32
static constexpr long OFF_NE    = 677316;    // [3520][128] f32
static constexpr long OFF_MO    = 1127876;   // [3520][128] f32

typedef __attribute__((ext_vector_type(8))) short short8v;   // 8 bf16 = 4 VGPR
typedef __attribute__((ext_vector_type(4))) float f32x4;     // MFMA 16x16 acc

__device__ __forceinline__ float ldf(const void* p, long i, int bf) {
  if (bf) {
    unsigned int u = (unsigned int)((const unsigned short*)p)[i];
    u <<= 16;
    return __uint_as_float(u);
  }
  return ((const float*)p)[i];
}

// 4 consecutive elems starting at i (i % 4 == 0)
__device__ __forceinline__ float4 ldf4(const void* p, long i, int bf) {
  float4 f;
  if (bf) {
    const unsigned short* q = (const unsigned short*)p + i;
    uint2 u = *(const uint2*)q;
    f.x = __uint_as_float(u.x << 16);
    f.y = __uint_as_float(u.x & 0xffff0000u);
    f.z = __uint_as_float(u.y << 16);
    f.w = __uint_as_float(u.y & 0xffff0000u);
  } else {
    f = *(const float4*)((const float*)p + i);
  }
  return f;
}

// bf16 raw uint2 -> float4 (identical bit path to ldf4's bf branch)
__device__ __forceinline__ float4 cvtbf4(uint2 u) {
  float4 f;
  f.x = __uint_as_float(u.x << 16);
  f.y = __uint_as_float(u.x & 0xffff0000u);
  f.z = __uint_as_float(u.y << 16);
  f.w = __uint_as_float(u.y & 0xffff0000u);
  return f;
}

__device__ __forceinline__ float eluf(float v) { return v > 0.f ? v : expm1f(v); }

// split f32 v into hi (truncated bf16 bits) + lo (RNE bf16 of remainder)
__device__ __forceinline__ void splitbf(float v, unsigned short& hi, unsigned short& lo) {
  unsigned int b = __float_as_uint(v);
  hi = (unsigned short)(b >> 16);
  float rm = v - __uint_as_float(b & 0xffff0000u);
  unsigned int rb = __float_as_uint(rm);
  lo = (unsigned short)((rb + 0x7fffu + ((rb >> 16) & 1u)) >> 16);
}

__device__ __forceinline__ float bfh(unsigned short u) {
  return __uint_as_float((unsigned int)u << 16);
}

// detect bf16-vs-f32 from first 256 ushorts of ent (wave-uniform result)
__device__ __forceinline__ int detect_bf(const void* ent, int tid, int* lds_cnt) {
  if (tid == 0) *lds_cnt = 0;
  __syncthreads();
  if (tid < 256) {
    unsigned short u = ((const unsigned short*)ent)[tid];
    int e = (u >> 7) & 0xFF;
    if (e >= 107 && e <= 146) atomicAdd(lds_cnt, 1);
  }
  __syncthreads();
  return (*lds_cnt >= 200) ? 1 : 0;
}

// ---- K1: convert weights (detect inlined) ---------------------------------
// MD 0: plain f32. MD 2: f32 K-packed [k/4][128][4]. MD 3: split-bf16 MFMA
// B pack [kt][n][32k] hi then lo (for 16x16x32: lane col=l&15, k=(l>>4)*8).
__global__ __launch_bounds__(256) void k_prep(
    const void* s0, const void* s1, const void* s2, const void* s3,
    const void* s4, const void* s5, const void* s6, const void* s7,
    const void* s8, const void* s9, const void* s10, const void* s11,
    const void* s12, const void* s13, const void* s14, const void* ent,
    float* ws) {
  __shared__ int cnt;
  const int bf = detect_bf(ent, threadIdx.x, &cnt);
  if (blockIdx.x == 0 && threadIdx.x == 0) ((int*)ws)[0] = bf;
  const void* srcs[15] = {s0,s1,s2,s3,s4,s5,s6,s7,s8,s9,s10,s11,s12,s13,s14};
  const int R[15] = {128,128,128,128,128,128,128,128,1,  1,  128,128,128,128,100};
  const int C[15] = {768,1,  128,1,  256,1,  128,1,  128,1,  256,1,  128,1,  128};
  const int MD[15]= {2,  0,  2,  0,  3,  0,  3,  0,  0,  0,  2,  0,  2,  0,  0};
  const long OFF[15] = {OFF_WNC1P,OFF_BNC1,OFF_WNC2P,OFF_BNC2,OFF_WANCP,OFF_BANC,
                        OFF_WAW1P,OFF_BAW1,OFF_WAW2,OFF_BAW2,OFF_WM1P,OFF_BM1,
                        OFF_WM2P,OFF_BM2,OFF_REL};
  const long total = 226689;
  for (long idx = (long)blockIdx.x * blockDim.x + threadIdx.x; idx < total;
       idx += (long)gridDim.x * blockDim.x) {
    long rem = idx;
    int s = 0;
    while (rem >= (long)R[s] * C[s]) { rem -= (long)R[s] * C[s]; s++; }
    float v = ldf(srcs[s], rem, bf);
    if (MD[s] == 2) {
      long r = rem / C[s], c = rem - r * C[s];
      ws[OFF[s] + (c >> 2) * 512 + r * 4 + (c & 3)] = v;
    } else if (MD[s] == 3) {
      long r = rem / C[s], c = rem - r * C[s];   // r = out n, c = k
      unsigned short hi, lo;
      splitbf(v, hi, lo);
      unsigned short* H = (unsigned short*)(ws + OFF[s]);
      unsigned short* L = H + (s == 4 ? 32768 : 16384);
      long id2 = ((c >> 5) * 128 + r) * 32 + (c & 31);
      H[id2] = hi;
      L[id2] = lo;
    } else {
      ws[OFF[s] + rem] = v;
    }
  }
}

// ---- K_fused: NEWS role (blocks 0..439) + ANCHOR role (blocks 440+) -------
// Shared-memory arena aliased by role (max 34000 B -> 4 blocks/CU).
__global__ __launch_bounds__(256, 4) void k_fused(
    const void* titles, const int* cand, const int* clk,
    const void* ent, const int* canda, const int* clka,
    const int* eadj, const int* radj, float* ws) {
  __shared__ __align__(16) char smem[34000];
  const int bf = ((const int*)ws)[0];
  int tid = threadIdx.x;

  if (blockIdx.x < NEWSBLK) {
    // ================= NEWS role: 8 title rows, 256 thr =================
    // half h (tid>>7) owns rows h*4..h*4+3; per-row math identical to the
    // original 128-thread kernel (same k order, same fma chain).
    float (*t)[768] = (float(*)[768])smem;                 // 24576 B
    float (*h1)[128] = (float(*)[128])(smem + 24576);      //  4096 B
    long r0 = (long)blockIdx.x * 8;
    for (int x = tid * 4; x < 8 * 768; x += 256 * 4) {
      int c = x / 768, k = x - c * 768;
      long i = r0 + c;
      int id = (i < NCAND) ? cand[i] : clk[i - NCAND];
      *(float4*)&t[c][k] = ldf4(titles, (long)id * 768 + k, bf);
    }
    __syncthreads();
    int j = tid & 127, half = tid >> 7;
    const float4* W1 = (const float4*)(ws + OFF_WNC1P);
    float acc[4];
#pragma unroll
    for (int c = 0; c < 4; c++) acc[c] = 0.f;
    for (int k4 = 0; k4 < 192; k4++) {
      float4 w = W1[k4 * 128 + j];
#pragma unroll
      for (int c = 0; c < 4; c++) {
        const float4 xv = *(const float4*)&t[half * 4 + c][k4 * 4];
        acc[c] += w.x * xv.x + w.y * xv.y + w.z * xv.z + w.w * xv.w;
      }
    }
    float b1 = ws[OFF_BNC1 + j];
#pragma unroll
    for (int c = 0; c < 4; c++) h1[half * 4 + c][j] = eluf(acc[c] + b1);
    __syncthreads();
    const float4* W2 = (const float4*)(ws + OFF_WNC2P);
    float a2[4];
#pragma unroll
    for (int c = 0; c < 4; c++) a2[c] = 0.f;
    for (int k4 = 0; k4 < 32; k4++) {
      float4 w = W2[k4 * 128 + j];
#pragma unroll
      for (int c = 0; c < 4; c++) {
        const float4 xv = *(const float4*)&h1[half * 4 + c][k4 * 4];
        a2[c] += w.x * xv.x + w.y * xv.y + w.z * xv.z + w.w * xv.w;
      }
    }
    float b2 = ws[OFF_BNC2 + j];
    float* NE = ws + OFF_NE;
#pragma unroll
    for (int c = 0; c < 4; c++)
      NE[(r0 + half * 4 + c) * 128 + j] = tanhf(a2[c] + b2);
    return;
  }

  // ================= ANCHOR role: 1 news = 20 anchors =================
  unsigned short (*XbH)[264] = (unsigned short(*)[264])smem;            // 10560 B
  unsigned short (*XbL)[264] = (unsigned short(*)[264])(smem + 10560);  // 10560 B
  unsigned short (*Hhi)[136] = (unsigned short(*)[136])(smem + 21120);  //  5440 B
  unsigned short (*Hlo)[136] = (unsigned short(*)[136])(smem + 26560);  //  5440 B
  int* NodeIdL = (int*)(smem + 32000);                                  //    80 B
  int* EAdjL   = (int*)(smem + 32080);                                  //   800 B
  int* RAdjL   = (int*)(smem + 32880);                                  //   800 B
  float (*LGp)[20] = (float(*)[20])(smem + 33680);                      //   320 B

  int blk = blockIdx.x - NEWSBLK;              // 0..3519
  int lane = tid & 63, wv = tid >> 6;
  int r16 = lane & 15, khh = lane >> 4;        // MFMA frag coords
  int lane32 = tid & 31, grp = tid >> 5;       // gather coords
  const float* relf = ws + OFF_REL;

  const unsigned short* WAH = (const unsigned short*)(ws + OFF_WANCP);
  const unsigned short* WAL = WAH + 32768;
  const unsigned short* W1H = (const unsigned short*)(ws + OFF_WAW1P);
  const unsigned short* W1L = W1H + 16384;

  // --- Prologue: cache node + adjacency ids in LDS ---
  if (tid < 20) {
    long n = (long)blk * 20 + tid;
    NodeIdL[tid] = (n < (long)NCAND * A_) ? canda[n] : clka[n - (long)NCAND * A_];
  }
  __syncthreads();
  if (tid < 200) {
    int rr = tid / 10, kk = tid - rr * 10;
    int nd = NodeIdL[rr];
    EAdjL[tid] = eadj[(long)nd * 10 + kk];
    RAdjL[tid] = radj[(long)nd * 10 + kk];
  }
  __syncthreads();

  // --- Gather phase ---
  auto consume = [&](int row, uint2 (&raw)[11]) {
    float4 x1 = cvtbf4(raw[0]);
    float4 a = {0.f, 0.f, 0.f, 0.f};
#pragma unroll
    for (int k = 0; k < 10; ++k) {
      float4 e = cvtbf4(raw[1 + k]);
      const float4 r = *(const float4*)&relf[(long)RAdjL[row * 10 + k] * 128 + lane32 * 4];
      a.x += e.x + r.x;
      a.y += e.y + r.y;
      a.z += e.z + r.z;
      a.w += e.w + r.w;
    }
    ushort4 h4, l4;
    splitbf(x1.x, h4.x, l4.x); splitbf(x1.y, h4.y, l4.y);
    splitbf(x1.z, h4.z, l4.z); splitbf(x1.w, h4.w, l4.w);
    *(ushort4*)&XbH[row][lane32 * 4] = h4;
    *(ushort4*)&XbL[row][lane32 * 4] = l4;
    splitbf(a.x, h4.x, l4.x); splitbf(a.y, h4.y, l4.y);
    splitbf(a.z, h4.z, l4.z); splitbf(a.w, h4.w, l4.w);
    *(ushort4*)&XbH[row][128 + lane32 * 4] = h4;
    *(ushort4*)&XbL[row][128 + lane32 * 4] = l4;
  };

  if (bf) {
    const unsigned short* entp = (const unsigned short*)ent;
    int row0 = grp, row1 = grp + 8, row2 = grp + 16;  // row2 only for wv<2
    uint2 raw0[11], raw1[11], raw2[11];
    raw0[0] = *(const uint2*)(entp + (long)NodeIdL[row0] * 128 + lane32 * 4);
#pragma unroll
    for (int k = 0; k < 10; ++k)
      raw0[1 + k] = *(const uint2*)(entp + (long)EAdjL[row0 * 10 + k] * 128 + lane32 * 4);
    raw1[0] = *(const uint2*)(entp + (long)NodeIdL[row1] * 128 + lane32 * 4);
#pragma unroll
    for (int k = 0; k < 10; ++k)
      raw1[1 + k] = *(const uint2*)(entp + (long)EAdjL[row1 * 10 + k] * 128 + lane32 * 4);
    if (wv < 2) {
      raw2[0] = *(const uint2*)(entp + (long)NodeIdL[row2] * 128 + lane32 * 4);
#pragma unroll
      for (int k = 0; k < 10; ++k)
        raw2[1 + k] = *(const uint2*)(entp + (long)EAdjL[row2 * 10 + k] * 128 + lane32 * 4);
    }
    __builtin_amdgcn_sched_barrier(0);
    consume(row0, raw0);
    consume(row1, raw1);
    if (wv < 2) consume(row2, raw2);
  } else {
    // f32 fallback (correctness path; bench input is bf16)
#pragma unroll
    for (int i = 0; i < 3; ++i) {
      int row = grp + i * 8;
      if (row < 20) {
        int node = NodeIdL[row];
        float4 x1 = ldf4(ent, (long)node * 128 + lane32 * 4, bf);
        float4 a = {0.f, 0.f, 0.f, 0.f};
#pragma unroll
        for (int k = 0; k < 10; ++k) {
          int an = EAdjL[row * 10 + k], rn = RAdjL[row * 10 + k];
          float4 e = ldf4(ent, (long)an * 128 + lane32 * 4, bf);
          const float4 r = *(const float4*)&relf[(long)rn * 128 + lane32 * 4];
          a.x += e.x + r.x;
          a.y += e.y + r.y;
          a.z += e.z + r.z;
          a.w += e.w + r.w;
        }
        ushort4 h4, l4;
        splitbf(x1.x, h4.x, l4.x); splitbf(x1.y, h4.y, l4.y);
        splitbf(x1.z, h4.z, l4.z); splitbf(x1.w, h4.w, l4.w);
        *(ushort4*)&XbH[row][lane32 * 4] = h4;
        *(ushort4*)&XbL[row][lane32 * 4] = l4;
        splitbf(a.x, h4.x, l4.x); splitbf(a.y, h4.y, l4.y);
        splitbf(a.z, h4.z, l4.z); splitbf(a.w, h4.w, l4.w);
        *(ushort4*)&XbH[row][128 + lane32 * 4] = h4;
        *(ushort4*)&XbL[row][128 + lane32 * 4] = l4;
      }
    }
  }
  __syncthreads();

  // --- Stage B: H = tanh(X @ Wanc^T + b), [20(pad32) x 256] @ [256->128] ---
  {
    int n0 = wv * 32 + r16, n1 = n0 + 16;
    int arow0 = r16, arow1 = 16 + (r16 & 3);   // mt=1 aliases rows 16-19
    f32x4 acc[2][2] = {};
    for (int kt = 0; kt < 8; ++kt) {
      long w0 = ((long)(kt * 128 + n0)) * 32 + khh * 8;
      long w1 = ((long)(kt * 128 + n1)) * 32 + khh * 8;
      short8v b0h = *(const short8v*)(WAH + w0);
      short8v b0l = *(const short8v*)(WAL + w0);
      short8v b1h = *(const short8v*)(WAH + w1);
      short8v b1l = *(const short8v*)(WAL + w1);
#pragma unroll
      for (int mt = 0; mt < 2; ++mt) {
        int ar = (mt == 0) ? arow0 : arow1;
        short8v ahi = *(const short8v*)&XbH[ar][kt * 32 + khh * 8];
        short8v alo = *(const short8v*)&XbL[ar][kt * 32 + khh * 8];
        acc[mt][0] = __builtin_amdgcn_mfma_f32_16x16x32_bf16(ahi, b0h, acc[mt][0], 0, 0, 0);
        acc[mt][0] = __builtin_amdgcn_mfma_f32_16x16x32_bf16(ahi, b0l, acc[mt][0], 0, 0, 0);
        acc[mt][0] = __builtin_amdgcn_mfma_f32_16x16x32_bf16(alo, b0h, acc[mt][0], 0, 0, 0);
        acc[mt][1] = __builtin_amdgcn_mfma_f32_16x16x32_bf16(ahi, b1h, acc[mt][1], 0, 0, 0);
        acc[mt][1] = __builtin_amdgcn_mfma_f32_16x16x32_bf16(ahi, b1l, acc[mt][1], 0, 0, 0);
        acc[mt][1] = __builtin_amdgcn_mfma_f32_16x16x32_bf16(alo, b1h, acc[mt][1], 0, 0, 0);
      }
    }
    float bc0 = ws[OFF_BANC + n0], bc1 = ws[OFF_BANC + n1];
#pragma unroll
    for (int mt = 0; mt < 2; ++mt)
#pragma unroll
      for (int j = 0; j < 4; ++j) {
        int r = mt * 16 + khh * 4 + j;
        if (r < 20) {
          unsigned short hi, lo;
          float h0 = tanhf(acc[mt][0][j] + bc0);
          splitbf(h0, hi, lo);
          Hhi[r][n0] = hi; Hlo[r][n0] = lo;
          float h1v = tanhf(acc[mt][1][j] + bc1);
          splitbf(h1v, hi, lo);
          Hhi[r][n1] = hi; Hlo[r][n1] = lo;
        }
      }
  }
  __syncthreads();

  // --- Stage C: logits = elu(H@Waw1^T+b1)@w2 + b2, [20(pad32)x128]@[128->128] ---
  {
    int n0 = wv * 32 + r16, n1 = n0 + 16;
    int hrow0 = r16, hrow1 = 16 + (r16 & 3);
    float b10 = ws[OFF_BAW1 + n0], b11 = ws[OFF_BAW1 + n1];
    float w20 = ws[OFF_WAW2 + n0], w21 = ws[OFF_WAW2 + n1];
    f32x4 ac[2][2] = {};
    for (int kt = 0; kt < 4; ++kt) {
      long w0 = ((long)(kt * 128 + n0)) * 32 + khh * 8;
      long w1 = ((long)(kt * 128 + n1)) * 32 + khh * 8;
      short8v b0h = *(const short8v*)(W1H + w0);
      short8v b0l = *(const short8v*)(W1L + w0);
      short8v b1h = *(const short8v*)(W1H + w1);
      short8v b1l = *(const short8v*)(W1L + w1);
#pragma unroll
      for (int mt = 0; mt < 2; ++mt) {
        int hr = (mt == 0) ? hrow0 : hrow1;
        short8v ahi = *(const short8v*)&Hhi[hr][kt * 32 + khh * 8];
        short8v alo = *(const short8v*)&Hlo[hr][kt * 32 + khh * 8];
        ac[mt][0] = __builtin_amdgcn_mfma_f32_16x16x32_bf16(ahi, b0h, ac[mt][0], 0, 0, 0);
        ac[mt][0] = __builtin_amdgcn_mfma_f32_16x16x32_bf16(ahi, b0l, ac[mt][0], 0, 0, 0);
        ac[mt][0] = __builtin_amdgcn_mfma_f32_16x16x32_bf16(alo, b0h, ac[mt][0], 0, 0, 0);
        ac[mt][1] = __builtin_amdgcn_mfma_f32_16x16x32_bf16(ahi, b1h, ac[mt][1], 0, 0, 0);
        ac[mt][1] = __builtin_amdgcn_mfma_f32_16x16x32_bf16(ahi, b1l, ac[mt][1], 0, 0, 0);
        ac[mt][1] = __builtin_amdgcn_mfma_f32_16x16x32_bf16(alo, b1h, ac[mt][1], 0, 0, 0);
      }
    }
#pragma unroll
    for (int mt = 0; mt < 2; ++mt)
#pragma unroll
      for (int j = 0; j < 4; ++j) {
        float v = eluf(ac[mt][0][j] + b10) * w20 + eluf(ac[mt][1][j] + b11) * w21;
        v += __shfl_xor(v, 1);
        v += __shfl_xor(v, 2);
        v += __shfl_xor(v, 4);
        v += __shfl_xor(v, 8);
        int r = mt * 16 + khh * 4 + j;
        if (r16 == 0 && r < 20) LGp[wv][r] = v;
      }
  }
  __syncthreads();

  // --- Stage D: softmax over 20 anchors + weighted sum (128 threads) ---
  if (tid < 128) {
    float bw2 = ws[OFF_BAW2];
    float e[20], mx = -1e30f;
#pragma unroll
    for (int a = 0; a < 20; ++a) {
      e[a] = LGp[0][a] + LGp[1][a] + LGp[2][a] + LGp[3][a] + bw2;
      mx = fmaxf(mx, e[a]);
    }
    float s = 0.f;
#pragma unroll
    for (int a = 0; a < 20; ++a) { e[a] = expf(e[a] - mx); s += e[a]; }
    float inv = 1.0f / s;
    float o = 0.f;
#pragma unroll
    for (int a = 0; a < 20; ++a)
      o += e[a] * (bfh(Hhi[a][tid]) + bfh(Hlo[a][tid]));
    float* AE = ws + OFF_AE;
    AE[(long)blk * 128 + tid] = o * inv;
  }
}

// ---- K5: final MLP --------------------------------------------------------
__global__ __launch_bounds__(256) void k_mlp(float* ws) {
  __shared__ __align__(16) float xt[16][256];
  __shared__ __align__(16) float h1[16][128];
  int tid = threadIdx.x;
  long r0 = (long)blockIdx.x * 16;
  const float* NE = ws + OFF_NE;
  const float* AE = ws + OFF_AE;
  for (int x = tid; x < 16 * 256; x += 256) {
    int c = x >> 8, k = x & 255;
    xt[c][k] = (k < 128) ? NE[(r0 + c) * 128 + k] : AE[(r0 + c) * 128 + (k - 128)];
  }
  __syncthreads();
  int j = tid & 127, half = tid >> 7;
  const float4* W1 = (const float4*)(ws + OFF_WM1P);
  float acc[8];
#pragma unroll
  for (int c = 0; c < 8; c++) acc[c] = 0.f;
  for (int k4 = 0; k4 < 64; k4++) {
    float4 w = W1[k4 * 128 + j];
#pragma unroll
    for (int c = 0; c < 8; c++) {
      const float4 xv = *(const float4*)&xt[half * 8 + c][k4 * 4];
      acc[c] += w.x * xv.x + w.y * xv.y + w.z * xv.z + w.w * xv.w;
    }
  }
  float b1 = ws[OFF_BM1 + j];
#pragma unroll
  for (int c = 0; c < 8; c++) h1[half * 8 + c][j] = eluf(acc[c] + b1);
  __syncthreads();
  const float4* W2 = (const float4*)(ws + OFF_WM2P);
  float a2[8];
#pragma unroll
  for (int c = 0; c < 8; c++) a2[c] = 0.f;
  for (int k4 = 0; k4 < 32; k4++) {
    float4 w = W2[k4 * 128 + j];
#pragma unroll
    for (int c = 0; c < 8; c++) {
      const float4 xv = *(const float4*)&h1[half * 8 + c][k4 * 4];
      a2[c] += w.x * xv.x + w.y * xv.y + w.z * xv.z + w.w * xv.w;
    }
  }
  float b2 = ws[OFF_BM2 + j];
  float* MO = ws + OFF_MO;
#pragma unroll
  for (int c = 0; c < 8; c++) MO[(r0 + half * 8 + c) * 128 + j] = eluf(a2[c] + b2);
}

// ---- K6: user mean + scores ----------------------------------------------
__global__ __launch_bounds__(128) void k_score(const float* ws, void* out) {
  const int bf = ((const int*)ws)[0];
  int b = blockIdx.x;
  int d = threadIdx.x;
  const float* MO = ws + OFF_MO;
  float u = 0.f;
  for (int t = 0; t < UC_; t++) u += MO[(long)(NCAND + b * UC_ + t) * 128 + d];
  u *= (1.0f / UC_);
  __shared__ float red[2];
  for (int s = 0; s < S_; s++) {
    float p = MO[(long)(b * S_ + s) * 128 + d] * u;
#pragma unroll
    for (int o = 32; o > 0; o >>= 1) p += __shfl_down(p, o, 64);
    if ((d & 63) == 0) red[d >> 6] = p;
    __syncthreads();
    if (d == 0) {
      float v = red[0] + red[1];
      if (bf)
        ((__hip_bfloat16*)out)[b * S_ + s] = __float2bfloat16(v);
      else
        ((float*)out)[b * S_ + s] = v;
    }
    __syncthreads();
  }
}

extern "C" void kernel_launch(void* const* d_in, const int* in_sizes, int n_in,
                              void* d_out, int out_size, void* d_ws, size_t ws_size,
                              hipStream_t stream) {
  (void)in_sizes; (void)n_in; (void)out_size; (void)ws_size;
  const void* titles = d_in[0];
  const void* ent    = d_in[1];
  const void* rel    = d_in[2];
  const void* Wnc1 = d_in[3];  const void* bnc1 = d_in[4];
  const void* Wnc2 = d_in[5];  const void* bnc2 = d_in[6];
  const void* Wanc = d_in[7];  const void* banc = d_in[8];
  const void* Waw1 = d_in[9];  const void* baw1 = d_in[10];
  const void* Waw2 = d_in[11]; const void* baw2 = d_in[12];
  const void* Wm1  = d_in[13]; const void* bm1  = d_in[14];
  const void* Wm2  = d_in[15]; const void* bm2  = d_in[16];
  const int* cand  = (const int*)d_in[17];
  const int* clk   = (const int*)d_in[18];
  const int* canda = (const int*)d_in[19];
  const int* clka  = (const int*)d_in[20];
  const int* eadj  = (const int*)d_in[21];
  const int* radj  = (const int*)d_in[22];
  float* ws = (float*)d_ws;

  k_prep<<<256, 256, 0, stream>>>(Wnc1, bnc1, Wnc2, bnc2, Wanc, banc, Waw1, baw1,
                                  Waw2, baw2, Wm1, bm1, Wm2, bm2, rel, ent, ws);
  k_fused<<<NEWSBLK + NNEWS, 256, 0, stream>>>(titles, cand, clk, ent, canda, clka,
                                               eadj, radj, ws);
  k_mlp<<<NNEWS / 16, 256, 0, stream>>>(ws);
  k_score<<<B_, 128, 0, stream>>>(ws, d_out);
}

// Round 16
// 256.331 us; speedup vs baseline: 1.0760x; 1.0760x over previous
//
#include <hip/hip_runtime.h>
#include <hip/hip_bf16.h>

// ---------------------------------------------------------------------------
// Recommender pipeline.
//  K1 prep   : detect bf16 inline (block0 publishes ws[0]); weights -> ws;
//              K-PACKED f32 (news/mlp); Wanc/Waw1 split-bf16 MFMA pack.
//  K_fused   : blocks 0-439 = NEWS role; blocks 440+ = ANCHOR role
//              (R14 fused gather+MFMA, byte-identical).
//              R15 post-mortem: WRITE 238MB = raw[11] arrays spilled to
//              scratch -- launch_bounds(256,4) cut VGPR cap to 128 and the
//              sched_barrier's 66-reg live range forced the spill. R16:
//              launch_bounds(256,3) (R14's proven no-spill point) and the
//              fence REMOVED (ignored at best, spill-trigger at worst).
//  K5 mlp    : elu(elu([news_e,AE]@Wm1^T+b)@Wm2^T+b)          [3520,128]
//  K6 score  : user mean + dot                                 [64,5]
//  All accumulation chains byte-identical to R12/R14 -> absmax 0.0.
// ---------------------------------------------------------------------------

#define B_ 64
#define S_ 5
#define UC_ 50
#define A_ 20
#define NCAND 320
#define NCLK 3200
#define NNEWS 3520
#define NANCH 70400
#define NEWSBLK 440   // NNEWS/8

// ws layout (float indices)
static constexpr long OFF_WNC1P = 64;        // [192][128][4] f32
static constexpr long OFF_BNC1  = 98368;
static constexpr long OFF_WNC2P = 98496;     // [32][128][4] f32
static constexpr long OFF_BNC2  = 114880;
static constexpr long OFF_WANCP = 115008;    // [8kt][128n][32k] bf16 hi + lo (65536 ushort)
static constexpr long OFF_BANC  = 147776;
static constexpr long OFF_WAW1P = 147904;    // [4kt][128n][32k] bf16 hi + lo (32768 ushort)
static constexpr long OFF_BAW1  = 164288;
static constexpr long OFF_WAW2  = 164416;    // [128]
static constexpr long OFF_BAW2  = 164544;    // [1]
static constexpr long OFF_WM1P  = 164548;    // [64][128][4] f32
static constexpr long OFF_BM1   = 197316;
static constexpr long OFF_WM2P  = 197444;    // [32][128][4] f32
static constexpr long OFF_BM2   = 213828;
static constexpr long OFF_REL   = 213956;    // [100][128] f32
static constexpr long OFF_AE    = 226756;    // [3520][128] f32
static constexpr long OFF_NE    = 677316;    // [3520][128] f32
static constexpr long OFF_MO    = 1127876;   // [3520][128] f32

typedef __attribute__((ext_vector_type(8))) short short8v;   // 8 bf16 = 4 VGPR
typedef __attribute__((ext_vector_type(4))) float f32x4;     // MFMA 16x16 acc

__device__ __forceinline__ float ldf(const void* p, long i, int bf) {
  if (bf) {
    unsigned int u = (unsigned int)((const unsigned short*)p)[i];
    u <<= 16;
    return __uint_as_float(u);
  }
  return ((const float*)p)[i];
}

// 4 consecutive elems starting at i (i % 4 == 0)
__device__ __forceinline__ float4 ldf4(const void* p, long i, int bf) {
  float4 f;
  if (bf) {
    const unsigned short* q = (const unsigned short*)p + i;
    uint2 u = *(const uint2*)q;
    f.x = __uint_as_float(u.x << 16);
    f.y = __uint_as_float(u.x & 0xffff0000u);
    f.z = __uint_as_float(u.y << 16);
    f.w = __uint_as_float(u.y & 0xffff0000u);
  } else {
    f = *(const float4*)((const float*)p + i);
  }
  return f;
}

// bf16 raw uint2 -> float4 (identical bit path to ldf4's bf branch)
__device__ __forceinline__ float4 cvtbf4(uint2 u) {
  float4 f;
  f.x = __uint_as_float(u.x << 16);
  f.y = __uint_as_float(u.x & 0xffff0000u);
  f.z = __uint_as_float(u.y << 16);
  f.w = __uint_as_float(u.y & 0xffff0000u);
  return f;
}

__device__ __forceinline__ float eluf(float v) { return v > 0.f ? v : expm1f(v); }

// split f32 v into hi (truncated bf16 bits) + lo (RNE bf16 of remainder)
__device__ __forceinline__ void splitbf(float v, unsigned short& hi, unsigned short& lo) {
  unsigned int b = __float_as_uint(v);
  hi = (unsigned short)(b >> 16);
  float rm = v - __uint_as_float(b & 0xffff0000u);
  unsigned int rb = __float_as_uint(rm);
  lo = (unsigned short)((rb + 0x7fffu + ((rb >> 16) & 1u)) >> 16);
}

__device__ __forceinline__ float bfh(unsigned short u) {
  return __uint_as_float((unsigned int)u << 16);
}

// detect bf16-vs-f32 from first 256 ushorts of ent (wave-uniform result)
__device__ __forceinline__ int detect_bf(const void* ent, int tid, int* lds_cnt) {
  if (tid == 0) *lds_cnt = 0;
  __syncthreads();
  if (tid < 256) {
    unsigned short u = ((const unsigned short*)ent)[tid];
    int e = (u >> 7) & 0xFF;
    if (e >= 107 && e <= 146) atomicAdd(lds_cnt, 1);
  }
  __syncthreads();
  return (*lds_cnt >= 200) ? 1 : 0;
}

// ---- K1: convert weights (detect inlined) ---------------------------------
// MD 0: plain f32. MD 2: f32 K-packed [k/4][128][4]. MD 3: split-bf16 MFMA
// B pack [kt][n][32k] hi then lo (for 16x16x32: lane col=l&15, k=(l>>4)*8).
__global__ __launch_bounds__(256) void k_prep(
    const void* s0, const void* s1, const void* s2, const void* s3,
    const void* s4, const void* s5, const void* s6, const void* s7,
    const void* s8, const void* s9, const void* s10, const void* s11,
    const void* s12, const void* s13, const void* s14, const void* ent,
    float* ws) {
  __shared__ int cnt;
  const int bf = detect_bf(ent, threadIdx.x, &cnt);
  if (blockIdx.x == 0 && threadIdx.x == 0) ((int*)ws)[0] = bf;
  const void* srcs[15] = {s0,s1,s2,s3,s4,s5,s6,s7,s8,s9,s10,s11,s12,s13,s14};
  const int R[15] = {128,128,128,128,128,128,128,128,1,  1,  128,128,128,128,100};
  const int C[15] = {768,1,  128,1,  256,1,  128,1,  128,1,  256,1,  128,1,  128};
  const int MD[15]= {2,  0,  2,  0,  3,  0,  3,  0,  0,  0,  2,  0,  2,  0,  0};
  const long OFF[15] = {OFF_WNC1P,OFF_BNC1,OFF_WNC2P,OFF_BNC2,OFF_WANCP,OFF_BANC,
                        OFF_WAW1P,OFF_BAW1,OFF_WAW2,OFF_BAW2,OFF_WM1P,OFF_BM1,
                        OFF_WM2P,OFF_BM2,OFF_REL};
  const long total = 226689;
  for (long idx = (long)blockIdx.x * blockDim.x + threadIdx.x; idx < total;
       idx += (long)gridDim.x * blockDim.x) {
    long rem = idx;
    int s = 0;
    while (rem >= (long)R[s] * C[s]) { rem -= (long)R[s] * C[s]; s++; }
    float v = ldf(srcs[s], rem, bf);
    if (MD[s] == 2) {
      long r = rem / C[s], c = rem - r * C[s];
      ws[OFF[s] + (c >> 2) * 512 + r * 4 + (c & 3)] = v;
    } else if (MD[s] == 3) {
      long r = rem / C[s], c = rem - r * C[s];   // r = out n, c = k
      unsigned short hi, lo;
      splitbf(v, hi, lo);
      unsigned short* H = (unsigned short*)(ws + OFF[s]);
      unsigned short* L = H + (s == 4 ? 32768 : 16384);
      long id2 = ((c >> 5) * 128 + r) * 32 + (c & 31);
      H[id2] = hi;
      L[id2] = lo;
    } else {
      ws[OFF[s] + rem] = v;
    }
  }
}

// ---- K_fused: NEWS role (blocks 0..439) + ANCHOR role (blocks 440+) -------
// Shared-memory arena aliased by role (max 34000 B); launch_bounds(256,3)
// = R14's proven no-spill operating point (VGPR cap ~170).
__global__ __launch_bounds__(256, 3) void k_fused(
    const void* titles, const int* cand, const int* clk,
    const void* ent, const int* canda, const int* clka,
    const int* eadj, const int* radj, float* ws) {
  __shared__ __align__(16) char smem[34000];
  const int bf = ((const int*)ws)[0];
  int tid = threadIdx.x;

  if (blockIdx.x < NEWSBLK) {
    // ================= NEWS role: 8 title rows, 256 thr =================
    // half h (tid>>7) owns rows h*4..h*4+3; per-row math identical to the
    // original 128-thread kernel (same k order, same fma chain).
    float (*t)[768] = (float(*)[768])smem;                 // 24576 B
    float (*h1)[128] = (float(*)[128])(smem + 24576);      //  4096 B
    long r0 = (long)blockIdx.x * 8;
    for (int x = tid * 4; x < 8 * 768; x += 256 * 4) {
      int c = x / 768, k = x - c * 768;
      long i = r0 + c;
      int id = (i < NCAND) ? cand[i] : clk[i - NCAND];
      *(float4*)&t[c][k] = ldf4(titles, (long)id * 768 + k, bf);
    }
    __syncthreads();
    int j = tid & 127, half = tid >> 7;
    const float4* W1 = (const float4*)(ws + OFF_WNC1P);
    float acc[4];
#pragma unroll
    for (int c = 0; c < 4; c++) acc[c] = 0.f;
    for (int k4 = 0; k4 < 192; k4++) {
      float4 w = W1[k4 * 128 + j];
#pragma unroll
      for (int c = 0; c < 4; c++) {
        const float4 xv = *(const float4*)&t[half * 4 + c][k4 * 4];
        acc[c] += w.x * xv.x + w.y * xv.y + w.z * xv.z + w.w * xv.w;
      }
    }
    float b1 = ws[OFF_BNC1 + j];
#pragma unroll
    for (int c = 0; c < 4; c++) h1[half * 4 + c][j] = eluf(acc[c] + b1);
    __syncthreads();
    const float4* W2 = (const float4*)(ws + OFF_WNC2P);
    float a2[4];
#pragma unroll
    for (int c = 0; c < 4; c++) a2[c] = 0.f;
    for (int k4 = 0; k4 < 32; k4++) {
      float4 w = W2[k4 * 128 + j];
#pragma unroll
      for (int c = 0; c < 4; c++) {
        const float4 xv = *(const float4*)&h1[half * 4 + c][k4 * 4];
        a2[c] += w.x * xv.x + w.y * xv.y + w.z * xv.z + w.w * xv.w;
      }
    }
    float b2 = ws[OFF_BNC2 + j];
    float* NE = ws + OFF_NE;
#pragma unroll
    for (int c = 0; c < 4; c++)
      NE[(r0 + half * 4 + c) * 128 + j] = tanhf(a2[c] + b2);
    return;
  }

  // ================= ANCHOR role: 1 news = 20 anchors =================
  unsigned short (*XbH)[264] = (unsigned short(*)[264])smem;            // 10560 B
  unsigned short (*XbL)[264] = (unsigned short(*)[264])(smem + 10560);  // 10560 B
  unsigned short (*Hhi)[136] = (unsigned short(*)[136])(smem + 21120);  //  5440 B
  unsigned short (*Hlo)[136] = (unsigned short(*)[136])(smem + 26560);  //  5440 B
  int* NodeIdL = (int*)(smem + 32000);                                  //    80 B
  int* EAdjL   = (int*)(smem + 32080);                                  //   800 B
  int* RAdjL   = (int*)(smem + 32880);                                  //   800 B
  float (*LGp)[20] = (float(*)[20])(smem + 33680);                      //   320 B

  int blk = blockIdx.x - NEWSBLK;              // 0..3519
  int lane = tid & 63, wv = tid >> 6;
  int r16 = lane & 15, khh = lane >> 4;        // MFMA frag coords
  int lane32 = tid & 31, grp = tid >> 5;       // gather coords
  const float* relf = ws + OFF_REL;

  const unsigned short* WAH = (const unsigned short*)(ws + OFF_WANCP);
  const unsigned short* WAL = WAH + 32768;
  const unsigned short* W1H = (const unsigned short*)(ws + OFF_WAW1P);
  const unsigned short* W1L = W1H + 16384;

  // --- Prologue: cache node + adjacency ids in LDS ---
  if (tid < 20) {
    long n = (long)blk * 20 + tid;
    NodeIdL[tid] = (n < (long)NCAND * A_) ? canda[n] : clka[n - (long)NCAND * A_];
  }
  __syncthreads();
  if (tid < 200) {
    int rr = tid / 10, kk = tid - rr * 10;
    int nd = NodeIdL[rr];
    EAdjL[tid] = eadj[(long)nd * 10 + kk];
    RAdjL[tid] = radj[(long)nd * 10 + kk];
  }
  __syncthreads();

  // --- Gather phase ---
  auto consume = [&](int row, uint2 (&raw)[11]) {
    float4 x1 = cvtbf4(raw[0]);
    float4 a = {0.f, 0.f, 0.f, 0.f};
#pragma unroll
    for (int k = 0; k < 10; ++k) {
      float4 e = cvtbf4(raw[1 + k]);
      const float4 r = *(const float4*)&relf[(long)RAdjL[row * 10 + k] * 128 + lane32 * 4];
      a.x += e.x + r.x;
      a.y += e.y + r.y;
      a.z += e.z + r.z;
      a.w += e.w + r.w;
    }
    ushort4 h4, l4;
    splitbf(x1.x, h4.x, l4.x); splitbf(x1.y, h4.y, l4.y);
    splitbf(x1.z, h4.z, l4.z); splitbf(x1.w, h4.w, l4.w);
    *(ushort4*)&XbH[row][lane32 * 4] = h4;
    *(ushort4*)&XbL[row][lane32 * 4] = l4;
    splitbf(a.x, h4.x, l4.x); splitbf(a.y, h4.y, l4.y);
    splitbf(a.z, h4.z, l4.z); splitbf(a.w, h4.w, l4.w);
    *(ushort4*)&XbH[row][128 + lane32 * 4] = h4;
    *(ushort4*)&XbL[row][128 + lane32 * 4] = l4;
  };

  if (bf) {
    const unsigned short* entp = (const unsigned short*)ent;
    int row0 = grp, row1 = grp + 8, row2 = grp + 16;  // row2 only for wv<2
    uint2 raw0[11], raw1[11], raw2[11];
    raw0[0] = *(const uint2*)(entp + (long)NodeIdL[row0] * 128 + lane32 * 4);
#pragma unroll
    for (int k = 0; k < 10; ++k)
      raw0[1 + k] = *(const uint2*)(entp + (long)EAdjL[row0 * 10 + k] * 128 + lane32 * 4);
    raw1[0] = *(const uint2*)(entp + (long)NodeIdL[row1] * 128 + lane32 * 4);
#pragma unroll
    for (int k = 0; k < 10; ++k)
      raw1[1 + k] = *(const uint2*)(entp + (long)EAdjL[row1 * 10 + k] * 128 + lane32 * 4);
    if (wv < 2) {
      raw2[0] = *(const uint2*)(entp + (long)NodeIdL[row2] * 128 + lane32 * 4);
#pragma unroll
      for (int k = 0; k < 10; ++k)
        raw2[1 + k] = *(const uint2*)(entp + (long)EAdjL[row2 * 10 + k] * 128 + lane32 * 4);
    }
    consume(row0, raw0);
    consume(row1, raw1);
    if (wv < 2) consume(row2, raw2);
  } else {
    // f32 fallback (correctness path; bench input is bf16)
#pragma unroll
    for (int i = 0; i < 3; ++i) {
      int row = grp + i * 8;
      if (row < 20) {
        int node = NodeIdL[row];
        float4 x1 = ldf4(ent, (long)node * 128 + lane32 * 4, bf);
        float4 a = {0.f, 0.f, 0.f, 0.f};
#pragma unroll
        for (int k = 0; k < 10; ++k) {
          int an = EAdjL[row * 10 + k], rn = RAdjL[row * 10 + k];
          float4 e = ldf4(ent, (long)an * 128 + lane32 * 4, bf);
          const float4 r = *(const float4*)&relf[(long)rn * 128 + lane32 * 4];
          a.x += e.x + r.x;
          a.y += e.y + r.y;
          a.z += e.z + r.z;
          a.w += e.w + r.w;
        }
        ushort4 h4, l4;
        splitbf(x1.x, h4.x, l4.x); splitbf(x1.y, h4.y, l4.y);
        splitbf(x1.z, h4.z, l4.z); splitbf(x1.w, h4.w, l4.w);
        *(ushort4*)&XbH[row][lane32 * 4] = h4;
        *(ushort4*)&XbL[row][lane32 * 4] = l4;
        splitbf(a.x, h4.x, l4.x); splitbf(a.y, h4.y, l4.y);
        splitbf(a.z, h4.z, l4.z); splitbf(a.w, h4.w, l4.w);
        *(ushort4*)&XbH[row][128 + lane32 * 4] = h4;
        *(ushort4*)&XbL[row][128 + lane32 * 4] = l4;
      }
    }
  }
  __syncthreads();

  // --- Stage B: H = tanh(X @ Wanc^T + b), [20(pad32) x 256] @ [256->128] ---
  {
    int n0 = wv * 32 + r16, n1 = n0 + 16;
    int arow0 = r16, arow1 = 16 + (r16 & 3);   // mt=1 aliases rows 16-19
    f32x4 acc[2][2] = {};
    for (int kt = 0; kt < 8; ++kt) {
      long w0 = ((long)(kt * 128 + n0)) * 32 + khh * 8;
      long w1 = ((long)(kt * 128 + n1)) * 32 + khh * 8;
      short8v b0h = *(const short8v*)(WAH + w0);
      short8v b0l = *(const short8v*)(WAL + w0);
      short8v b1h = *(const short8v*)(WAH + w1);
      short8v b1l = *(const short8v*)(WAL + w1);
#pragma unroll
      for (int mt = 0; mt < 2; ++mt) {
        int ar = (mt == 0) ? arow0 : arow1;
        short8v ahi = *(const short8v*)&XbH[ar][kt * 32 + khh * 8];
        short8v alo = *(const short8v*)&XbL[ar][kt * 32 + khh * 8];
        acc[mt][0] = __builtin_amdgcn_mfma_f32_16x16x32_bf16(ahi, b0h, acc[mt][0], 0, 0, 0);
        acc[mt][0] = __builtin_amdgcn_mfma_f32_16x16x32_bf16(ahi, b0l, acc[mt][0], 0, 0, 0);
        acc[mt][0] = __builtin_amdgcn_mfma_f32_16x16x32_bf16(alo, b0h, acc[mt][0], 0, 0, 0);
        acc[mt][1] = __builtin_amdgcn_mfma_f32_16x16x32_bf16(ahi, b1h, acc[mt][1], 0, 0, 0);
        acc[mt][1] = __builtin_amdgcn_mfma_f32_16x16x32_bf16(ahi, b1l, acc[mt][1], 0, 0, 0);
        acc[mt][1] = __builtin_amdgcn_mfma_f32_16x16x32_bf16(alo, b1h, acc[mt][1], 0, 0, 0);
      }
    }
    float bc0 = ws[OFF_BANC + n0], bc1 = ws[OFF_BANC + n1];
#pragma unroll
    for (int mt = 0; mt < 2; ++mt)
#pragma unroll
      for (int j = 0; j < 4; ++j) {
        int r = mt * 16 + khh * 4 + j;
        if (r < 20) {
          unsigned short hi, lo;
          float h0 = tanhf(acc[mt][0][j] + bc0);
          splitbf(h0, hi, lo);
          Hhi[r][n0] = hi; Hlo[r][n0] = lo;
          float h1v = tanhf(acc[mt][1][j] + bc1);
          splitbf(h1v, hi, lo);
          Hhi[r][n1] = hi; Hlo[r][n1] = lo;
        }
      }
  }
  __syncthreads();

  // --- Stage C: logits = elu(H@Waw1^T+b1)@w2 + b2, [20(pad32)x128]@[128->128] ---
  {
    int n0 = wv * 32 + r16, n1 = n0 + 16;
    int hrow0 = r16, hrow1 = 16 + (r16 & 3);
    float b10 = ws[OFF_BAW1 + n0], b11 = ws[OFF_BAW1 + n1];
    float w20 = ws[OFF_WAW2 + n0], w21 = ws[OFF_WAW2 + n1];
    f32x4 ac[2][2] = {};
    for (int kt = 0; kt < 4; ++kt) {
      long w0 = ((long)(kt * 128 + n0)) * 32 + khh * 8;
      long w1 = ((long)(kt * 128 + n1)) * 32 + khh * 8;
      short8v b0h = *(const short8v*)(W1H + w0);
      short8v b0l = *(const short8v*)(W1L + w0);
      short8v b1h = *(const short8v*)(W1H + w1);
      short8v b1l = *(const short8v*)(W1L + w1);
#pragma unroll
      for (int mt = 0; mt < 2; ++mt) {
        int hr = (mt == 0) ? hrow0 : hrow1;
        short8v ahi = *(const short8v*)&Hhi[hr][kt * 32 + khh * 8];
        short8v alo = *(const short8v*)&Hlo[hr][kt * 32 + khh * 8];
        ac[mt][0] = __builtin_amdgcn_mfma_f32_16x16x32_bf16(ahi, b0h, ac[mt][0], 0, 0, 0);
        ac[mt][0] = __builtin_amdgcn_mfma_f32_16x16x32_bf16(ahi, b0l, ac[mt][0], 0, 0, 0);
        ac[mt][0] = __builtin_amdgcn_mfma_f32_16x16x32_bf16(alo, b0h, ac[mt][0], 0, 0, 0);
        ac[mt][1] = __builtin_amdgcn_mfma_f32_16x16x32_bf16(ahi, b1h, ac[mt][1], 0, 0, 0);
        ac[mt][1] = __builtin_amdgcn_mfma_f32_16x16x32_bf16(ahi, b1l, ac[mt][1], 0, 0, 0);
        ac[mt][1] = __builtin_amdgcn_mfma_f32_16x16x32_bf16(alo, b1h, ac[mt][1], 0, 0, 0);
      }
    }
#pragma unroll
    for (int mt = 0; mt < 2; ++mt)
#pragma unroll
      for (int j = 0; j < 4; ++j) {
        float v = eluf(ac[mt][0][j] + b10) * w20 + eluf(ac[mt][1][j] + b11) * w21;
        v += __shfl_xor(v, 1);
        v += __shfl_xor(v, 2);
        v += __shfl_xor(v, 4);
        v += __shfl_xor(v, 8);
        int r = mt * 16 + khh * 4 + j;
        if (r16 == 0 && r < 20) LGp[wv][r] = v;
      }
  }
  __syncthreads();

  // --- Stage D: softmax over 20 anchors + weighted sum (128 threads) ---
  if (tid < 128) {
    float bw2 = ws[OFF_BAW2];
    float e[20], mx = -1e30f;
#pragma unroll
    for (int a = 0; a < 20; ++a) {
      e[a] = LGp[0][a] + LGp[1][a] + LGp[2][a] + LGp[3][a] + bw2;
      mx = fmaxf(mx, e[a]);
    }
    float s = 0.f;
#pragma unroll
    for (int a = 0; a < 20; ++a) { e[a] = expf(e[a] - mx); s += e[a]; }
    float inv = 1.0f / s;
    float o = 0.f;
#pragma unroll
    for (int a = 0; a < 20; ++a)
      o += e[a] * (bfh(Hhi[a][tid]) + bfh(Hlo[a][tid]));
    float* AE = ws + OFF_AE;
    AE[(long)blk * 128 + tid] = o * inv;
  }
}

// ---- K5: final MLP --------------------------------------------------------
__global__ __launch_bounds__(256) void k_mlp(float* ws) {
  __shared__ __align__(16) float xt[16][256];
  __shared__ __align__(16) float h1[16][128];
  int tid = threadIdx.x;
  long r0 = (long)blockIdx.x * 16;
  const float* NE = ws + OFF_NE;
  const float* AE = ws + OFF_AE;
  for (int x = tid; x < 16 * 256; x += 256) {
    int c = x >> 8, k = x & 255;
    xt[c][k] = (k < 128) ? NE[(r0 + c) * 128 + k] : AE[(r0 + c) * 128 + (k - 128)];
  }
  __syncthreads();
  int j = tid & 127, half = tid >> 7;
  const float4* W1 = (const float4*)(ws + OFF_WM1P);
  float acc[8];
#pragma unroll
  for (int c = 0; c < 8; c++) acc[c] = 0.f;
  for (int k4 = 0; k4 < 64; k4++) {
    float4 w = W1[k4 * 128 + j];
#pragma unroll
    for (int c = 0; c < 8; c++) {
      const float4 xv = *(const float4*)&xt[half * 8 + c][k4 * 4];
      acc[c] += w.x * xv.x + w.y * xv.y + w.z * xv.z + w.w * xv.w;
    }
  }
  float b1 = ws[OFF_BM1 + j];
#pragma unroll
  for (int c = 0; c < 8; c++) h1[half * 8 + c][j] = eluf(acc[c] + b1);
  __syncthreads();
  const float4* W2 = (const float4*)(ws + OFF_WM2P);
  float a2[8];
#pragma unroll
  for (int c = 0; c < 8; c++) a2[c] = 0.f;
  for (int k4 = 0; k4 < 32; k4++) {
    float4 w = W2[k4 * 128 + j];
#pragma unroll
    for (int c = 0; c < 8; c++) {
      const float4 xv = *(const float4*)&h1[half * 8 + c][k4 * 4];
      a2[c] += w.x * xv.x + w.y * xv.y + w.z * xv.z + w.w * xv.w;
    }
  }
  float b2 = ws[OFF_BM2 + j];
  float* MO = ws + OFF_MO;
#pragma unroll
  for (int c = 0; c < 8; c++) MO[(r0 + half * 8 + c) * 128 + j] = eluf(a2[c] + b2);
}

// ---- K6: user mean + scores ----------------------------------------------
__global__ __launch_bounds__(128) void k_score(const float* ws, void* out) {
  const int bf = ((const int*)ws)[0];
  int b = blockIdx.x;
  int d = threadIdx.x;
  const float* MO = ws + OFF_MO;
  float u = 0.f;
  for (int t = 0; t < UC_; t++) u += MO[(long)(NCAND + b * UC_ + t) * 128 + d];
  u *= (1.0f / UC_);
  __shared__ float red[2];
  for (int s = 0; s < S_; s++) {
    float p = MO[(long)(b * S_ + s) * 128 + d] * u;
#pragma unroll
    for (int o = 32; o > 0; o >>= 1) p += __shfl_down(p, o, 64);
    if ((d & 63) == 0) red[d >> 6] = p;
    __syncthreads();
    if (d == 0) {
      float v = red[0] + red[1];
      if (bf)
        ((__hip_bfloat16*)out)[b * S_ + s] = __float2bfloat16(v);
      else
        ((float*)out)[b * S_ + s] = v;
    }
    __syncthreads();
  }
}

extern "C" void kernel_launch(void* const* d_in, const int* in_sizes, int n_in,
                              void* d_out, int out_size, void* d_ws, size_t ws_size,
                              hipStream_t stream) {
  (void)in_sizes; (void)n_in; (void)out_size; (void)ws_size;
  const void* titles = d_in[0];
  const void* ent    = d_in[1];
  const void* rel    = d_in[2];
  const void* Wnc1 = d_in[3];  const void* bnc1 = d_in[4];
  const void* Wnc2 = d_in[5];  const void* bnc2 = d_in[6];
  const void* Wanc = d_in[7];  const void* banc = d_in[8];
  const void* Waw1 = d_in[9];  const void* baw1 = d_in[10];
  const void* Waw2 = d_in[11]; const void* baw2 = d_in[12];
  const void* Wm1  = d_in[13]; const void* bm1  = d_in[14];
  const void* Wm2  = d_in[15]; const void* bm2  = d_in[16];
  const int* cand  = (const int*)d_in[17];
  const int* clk   = (const int*)d_in[18];
  const int* canda = (const int*)d_in[19];
  const int* clka  = (const int*)d_in[20];
  const int* eadj  = (const int*)d_in[21];
  const int* radj  = (const int*)d_in[22];
  float* ws = (float*)d_ws;

  k_prep<<<256, 256, 0, stream>>>(Wnc1, bnc1, Wnc2, bnc2, Wanc, banc, Waw1, baw1,
                                  Waw2, baw2, Wm1, bm1, Wm2, bm2, rel, ent, ws);
  k_fused<<<NEWSBLK + NNEWS, 256, 0, stream>>>(titles, cand, clk, ent, canda, clka,
                                               eadj, radj, ws);
  k_mlp<<<NNEWS / 16, 256, 0, stream>>>(ws);
  k_score<<<B_, 128, 0, stream>>>(ws, d_out);
}

// Round 17
// 201.621 us; speedup vs baseline: 1.3679x; 1.2713x over previous
//
#include <hip/hip_runtime.h>
#include <hip/hip_bf16.h>

// ---------------------------------------------------------------------------
// Recommender pipeline.
//  K1 prep   : detect bf16 inline (block0 publishes ws[0]); weights -> ws;
//              K-PACKED f32 (news/mlp); Wanc/Waw1 split-bf16 MFMA pack.
//  K2 news   : news_e = tanh(elu(title@W1^T+b)@W2^T+b)  (128 thr, original)
//  K_anchor  : R14 fused gather+MFMA, standalone (R15/R16 post-mortem:
//              co-branching news into the same kernel perturbed regalloc ->
//              164-238MB scratch spill; rule: roles must not share a
//              kernel's allocator). No sched_barrier (proven ignored or
//              spill-trigger). launch_bounds(256,4): LDS 34.3KB -> 4 blk/CU,
//              VGPR ~68 << 128 cap -> no spill.
//  K5 mlp    : elu(elu([news_e,AE]@Wm1^T+b)@Wm2^T+b)          [3520,128]
//  K6 score  : user mean + dot                                 [64,5]
//  All accumulation chains byte-identical to R12/R14 -> absmax 0.0.
// ---------------------------------------------------------------------------

#define B_ 64
#define S_ 5
#define UC_ 50
#define A_ 20
#define NCAND 320
#define NCLK 3200
#define NNEWS 3520
#define NANCH 70400

// ws layout (float indices)
static constexpr long OFF_WNC1P = 64;        // [192][128][4] f32
static constexpr long OFF_BNC1  = 98368;
static constexpr long OFF_WNC2P = 98496;     // [32][128][4] f32
static constexpr long OFF_BNC2  = 114880;
static constexpr long OFF_WANCP = 115008;    // [8kt][128n][32k] bf16 hi + lo (65536 ushort)
static constexpr long OFF_BANC  = 147776;
static constexpr long OFF_WAW1P = 147904;    // [4kt][128n][32k] bf16 hi + lo (32768 ushort)
static constexpr long OFF_BAW1  = 164288;
static constexpr long OFF_WAW2  = 164416;    // [128]
static constexpr long OFF_BAW2  = 164544;    // [1]
static constexpr long OFF_WM1P  = 164548;    // [64][128][4] f32
static constexpr long OFF_BM1   = 197316;
static constexpr long OFF_WM2P  = 197444;    // [32][128][4] f32
static constexpr long OFF_BM2   = 213828;
static constexpr long OFF_REL   = 213956;    // [100][128] f32
static constexpr long OFF_AE    = 226756;    // [3520][128] f32
static constexpr long OFF_NE    = 677316;    // [3520][128] f32
static constexpr long OFF_MO    = 1127876;   // [3520][128] f32

typedef __attribute__((ext_vector_type(8))) short short8v;   // 8 bf16 = 4 VGPR
typedef __attribute__((ext_vector_type(4))) float f32x4;     // MFMA 16x16 acc

__device__ __forceinline__ float ldf(const void* p, long i, int bf) {
  if (bf) {
    unsigned int u = (unsigned int)((const unsigned short*)p)[i];
    u <<= 16;
    return __uint_as_float(u);
  }
  return ((const float*)p)[i];
}

// 4 consecutive elems starting at i (i % 4 == 0)
__device__ __forceinline__ float4 ldf4(const void* p, long i, int bf) {
  float4 f;
  if (bf) {
    const unsigned short* q = (const unsigned short*)p + i;
    uint2 u = *(const uint2*)q;
    f.x = __uint_as_float(u.x << 16);
    f.y = __uint_as_float(u.x & 0xffff0000u);
    f.z = __uint_as_float(u.y << 16);
    f.w = __uint_as_float(u.y & 0xffff0000u);
  } else {
    f = *(const float4*)((const float*)p + i);
  }
  return f;
}

// bf16 raw uint2 -> float4 (identical bit path to ldf4's bf branch)
__device__ __forceinline__ float4 cvtbf4(uint2 u) {
  float4 f;
  f.x = __uint_as_float(u.x << 16);
  f.y = __uint_as_float(u.x & 0xffff0000u);
  f.z = __uint_as_float(u.y << 16);
  f.w = __uint_as_float(u.y & 0xffff0000u);
  return f;
}

__device__ __forceinline__ float eluf(float v) { return v > 0.f ? v : expm1f(v); }

// split f32 v into hi (truncated bf16 bits) + lo (RNE bf16 of remainder)
__device__ __forceinline__ void splitbf(float v, unsigned short& hi, unsigned short& lo) {
  unsigned int b = __float_as_uint(v);
  hi = (unsigned short)(b >> 16);
  float rm = v - __uint_as_float(b & 0xffff0000u);
  unsigned int rb = __float_as_uint(rm);
  lo = (unsigned short)((rb + 0x7fffu + ((rb >> 16) & 1u)) >> 16);
}

__device__ __forceinline__ float bfh(unsigned short u) {
  return __uint_as_float((unsigned int)u << 16);
}

// detect bf16-vs-f32 from first 256 ushorts of ent (wave-uniform result)
__device__ __forceinline__ int detect_bf(const void* ent, int tid, int* lds_cnt) {
  if (tid == 0) *lds_cnt = 0;
  __syncthreads();
  if (tid < 256) {
    unsigned short u = ((const unsigned short*)ent)[tid];
    int e = (u >> 7) & 0xFF;
    if (e >= 107 && e <= 146) atomicAdd(lds_cnt, 1);
  }
  __syncthreads();
  return (*lds_cnt >= 200) ? 1 : 0;
}

// ---- K1: convert weights (detect inlined) ---------------------------------
// MD 0: plain f32. MD 2: f32 K-packed [k/4][128][4]. MD 3: split-bf16 MFMA
// B pack [kt][n][32k] hi then lo (for 16x16x32: lane col=l&15, k=(l>>4)*8).
__global__ __launch_bounds__(256) void k_prep(
    const void* s0, const void* s1, const void* s2, const void* s3,
    const void* s4, const void* s5, const void* s6, const void* s7,
    const void* s8, const void* s9, const void* s10, const void* s11,
    const void* s12, const void* s13, const void* s14, const void* ent,
    float* ws) {
  __shared__ int cnt;
  const int bf = detect_bf(ent, threadIdx.x, &cnt);
  if (blockIdx.x == 0 && threadIdx.x == 0) ((int*)ws)[0] = bf;
  const void* srcs[15] = {s0,s1,s2,s3,s4,s5,s6,s7,s8,s9,s10,s11,s12,s13,s14};
  const int R[15] = {128,128,128,128,128,128,128,128,1,  1,  128,128,128,128,100};
  const int C[15] = {768,1,  128,1,  256,1,  128,1,  128,1,  256,1,  128,1,  128};
  const int MD[15]= {2,  0,  2,  0,  3,  0,  3,  0,  0,  0,  2,  0,  2,  0,  0};
  const long OFF[15] = {OFF_WNC1P,OFF_BNC1,OFF_WNC2P,OFF_BNC2,OFF_WANCP,OFF_BANC,
                        OFF_WAW1P,OFF_BAW1,OFF_WAW2,OFF_BAW2,OFF_WM1P,OFF_BM1,
                        OFF_WM2P,OFF_BM2,OFF_REL};
  const long total = 226689;
  for (long idx = (long)blockIdx.x * blockDim.x + threadIdx.x; idx < total;
       idx += (long)gridDim.x * blockDim.x) {
    long rem = idx;
    int s = 0;
    while (rem >= (long)R[s] * C[s]) { rem -= (long)R[s] * C[s]; s++; }
    float v = ldf(srcs[s], rem, bf);
    if (MD[s] == 2) {
      long r = rem / C[s], c = rem - r * C[s];
      ws[OFF[s] + (c >> 2) * 512 + r * 4 + (c & 3)] = v;
    } else if (MD[s] == 3) {
      long r = rem / C[s], c = rem - r * C[s];   // r = out n, c = k
      unsigned short hi, lo;
      splitbf(v, hi, lo);
      unsigned short* H = (unsigned short*)(ws + OFF[s]);
      unsigned short* L = H + (s == 4 ? 32768 : 16384);
      long id2 = ((c >> 5) * 128 + r) * 32 + (c & 31);
      H[id2] = hi;
      L[id2] = lo;
    } else {
      ws[OFF[s] + rem] = v;
    }
  }
}

// ---- K2: news title MLP (128 thr, 8 rows, acc[8]) ------------------------
__global__ __launch_bounds__(128) void k_news(const void* titles, const int* cand,
                                              const int* clk, float* ws) {
  const int bf = ((const int*)ws)[0];
  __shared__ __align__(16) float t[8][768];
  __shared__ __align__(16) float h1[8][128];
  int tid = threadIdx.x;
  long r0 = (long)blockIdx.x * 8;
  for (int x = tid * 4; x < 8 * 768; x += 128 * 4) {
    int c = x / 768, k = x - c * 768;
    long i = r0 + c;
    int id = (i < NCAND) ? cand[i] : clk[i - NCAND];
    *(float4*)&t[c][k] = ldf4(titles, (long)id * 768 + k, bf);
  }
  __syncthreads();
  int j = tid;
  const float4* W1 = (const float4*)(ws + OFF_WNC1P);
  float acc[8];
#pragma unroll
  for (int c = 0; c < 8; c++) acc[c] = 0.f;
  for (int k4 = 0; k4 < 192; k4++) {
    float4 w = W1[k4 * 128 + j];
#pragma unroll
    for (int c = 0; c < 8; c++) {
      const float4 xv = *(const float4*)&t[c][k4 * 4];
      acc[c] += w.x * xv.x + w.y * xv.y + w.z * xv.z + w.w * xv.w;
    }
  }
  float b1 = ws[OFF_BNC1 + j];
#pragma unroll
  for (int c = 0; c < 8; c++) h1[c][j] = eluf(acc[c] + b1);
  __syncthreads();
  const float4* W2 = (const float4*)(ws + OFF_WNC2P);
  float a2[8];
#pragma unroll
  for (int c = 0; c < 8; c++) a2[c] = 0.f;
  for (int k4 = 0; k4 < 32; k4++) {
    float4 w = W2[k4 * 128 + j];
#pragma unroll
    for (int c = 0; c < 8; c++) {
      const float4 xv = *(const float4*)&h1[c][k4 * 4];
      a2[c] += w.x * xv.x + w.y * xv.y + w.z * xv.z + w.w * xv.w;
    }
  }
  float b2 = ws[OFF_BNC2 + j];
  float* NE = ws + OFF_NE;
#pragma unroll
  for (int c = 0; c < 8; c++) NE[(r0 + c) * 128 + j] = tanhf(a2[c] + b2);
}

// ---- K_anchor: fused gather + MFMA anchor GEMMs + softmax -----------------
// block = 1 news = 20 anchor rows, grid 3520, 256 thr = 4 waves.
// Gather: 8 groups; waves 0-1 own rows {g, g+8, g+16}, waves 2-3 {g, g+8}.
// LDS 34.3KB -> launch_bounds(256,4) = 4 blocks/CU (16 waves/CU); VGPR ~68
// fits the 128 cap with margin -> no spill. Frag maps (m89): A row=l&15,
// k=(l>>4)*8; D col=l&15, row=(l>>4)*4+j. mt=1 A-rows alias 16+(r16&3).
__global__ __launch_bounds__(256, 4) void k_anchor(const void* ent, const int* canda,
                                                   const int* clka, const int* eadj,
                                                   const int* radj, float* ws) {
  __shared__ __align__(16) unsigned short XbH[20][264];   // 10.3 KB
  __shared__ __align__(16) unsigned short XbL[20][264];   // 10.3 KB
  __shared__ __align__(16) unsigned short Hhi[20][136];   // 5.3 KB
  __shared__ __align__(16) unsigned short Hlo[20][136];   // 5.3 KB
  __shared__ int NodeIdL[20];
  __shared__ int EAdjL[200];
  __shared__ int RAdjL[200];
  __shared__ float LGp[4][20];

  const int bf = ((const int*)ws)[0];
  int tid = threadIdx.x;
  int lane = tid & 63, wv = tid >> 6;
  int r16 = lane & 15, khh = lane >> 4;       // MFMA frag coords
  int lane32 = tid & 31, grp = tid >> 5;      // gather coords
  const float* relf = ws + OFF_REL;

  const unsigned short* WAH = (const unsigned short*)(ws + OFF_WANCP);
  const unsigned short* WAL = WAH + 32768;
  const unsigned short* W1H = (const unsigned short*)(ws + OFF_WAW1P);
  const unsigned short* W1L = W1H + 16384;

  // --- Prologue: cache node + adjacency ids in LDS ---
  if (tid < 20) {
    long n = (long)blockIdx.x * 20 + tid;
    NodeIdL[tid] = (n < (long)NCAND * A_) ? canda[n] : clka[n - (long)NCAND * A_];
  }
  __syncthreads();
  if (tid < 200) {
    int rr = tid / 10, kk = tid - rr * 10;
    int nd = NodeIdL[rr];
    EAdjL[tid] = eadj[(long)nd * 10 + kk];
    RAdjL[tid] = radj[(long)nd * 10 + kk];
  }
  __syncthreads();

  // --- Gather phase ---
  auto consume = [&](int row, uint2 (&raw)[11]) {
    float4 x1 = cvtbf4(raw[0]);
    float4 a = {0.f, 0.f, 0.f, 0.f};
#pragma unroll
    for (int k = 0; k < 10; ++k) {
      float4 e = cvtbf4(raw[1 + k]);
      const float4 r = *(const float4*)&relf[(long)RAdjL[row * 10 + k] * 128 + lane32 * 4];
      a.x += e.x + r.x;
      a.y += e.y + r.y;
      a.z += e.z + r.z;
      a.w += e.w + r.w;
    }
    ushort4 h4, l4;
    splitbf(x1.x, h4.x, l4.x); splitbf(x1.y, h4.y, l4.y);
    splitbf(x1.z, h4.z, l4.z); splitbf(x1.w, h4.w, l4.w);
    *(ushort4*)&XbH[row][lane32 * 4] = h4;
    *(ushort4*)&XbL[row][lane32 * 4] = l4;
    splitbf(a.x, h4.x, l4.x); splitbf(a.y, h4.y, l4.y);
    splitbf(a.z, h4.z, l4.z); splitbf(a.w, h4.w, l4.w);
    *(ushort4*)&XbH[row][128 + lane32 * 4] = h4;
    *(ushort4*)&XbL[row][128 + lane32 * 4] = l4;
  };

  if (bf) {
    const unsigned short* entp = (const unsigned short*)ent;
    int row0 = grp, row1 = grp + 8, row2 = grp + 16;  // row2 only for wv<2
    uint2 raw0[11], raw1[11], raw2[11];
    raw0[0] = *(const uint2*)(entp + (long)NodeIdL[row0] * 128 + lane32 * 4);
#pragma unroll
    for (int k = 0; k < 10; ++k)
      raw0[1 + k] = *(const uint2*)(entp + (long)EAdjL[row0 * 10 + k] * 128 + lane32 * 4);
    raw1[0] = *(const uint2*)(entp + (long)NodeIdL[row1] * 128 + lane32 * 4);
#pragma unroll
    for (int k = 0; k < 10; ++k)
      raw1[1 + k] = *(const uint2*)(entp + (long)EAdjL[row1 * 10 + k] * 128 + lane32 * 4);
    if (wv < 2) {
      raw2[0] = *(const uint2*)(entp + (long)NodeIdL[row2] * 128 + lane32 * 4);
#pragma unroll
      for (int k = 0; k < 10; ++k)
        raw2[1 + k] = *(const uint2*)(entp + (long)EAdjL[row2 * 10 + k] * 128 + lane32 * 4);
    }
    consume(row0, raw0);
    consume(row1, raw1);
    if (wv < 2) consume(row2, raw2);
  } else {
    // f32 fallback (correctness path; bench input is bf16)
#pragma unroll
    for (int i = 0; i < 3; ++i) {
      int row = grp + i * 8;
      if (row < 20) {
        int node = NodeIdL[row];
        float4 x1 = ldf4(ent, (long)node * 128 + lane32 * 4, bf);
        float4 a = {0.f, 0.f, 0.f, 0.f};
#pragma unroll
        for (int k = 0; k < 10; ++k) {
          int an = EAdjL[row * 10 + k], rn = RAdjL[row * 10 + k];
          float4 e = ldf4(ent, (long)an * 128 + lane32 * 4, bf);
          const float4 r = *(const float4*)&relf[(long)rn * 128 + lane32 * 4];
          a.x += e.x + r.x;
          a.y += e.y + r.y;
          a.z += e.z + r.z;
          a.w += e.w + r.w;
        }
        ushort4 h4, l4;
        splitbf(x1.x, h4.x, l4.x); splitbf(x1.y, h4.y, l4.y);
        splitbf(x1.z, h4.z, l4.z); splitbf(x1.w, h4.w, l4.w);
        *(ushort4*)&XbH[row][lane32 * 4] = h4;
        *(ushort4*)&XbL[row][lane32 * 4] = l4;
        splitbf(a.x, h4.x, l4.x); splitbf(a.y, h4.y, l4.y);
        splitbf(a.z, h4.z, l4.z); splitbf(a.w, h4.w, l4.w);
        *(ushort4*)&XbH[row][128 + lane32 * 4] = h4;
        *(ushort4*)&XbL[row][128 + lane32 * 4] = l4;
      }
    }
  }
  __syncthreads();

  // --- Stage B: H = tanh(X @ Wanc^T + b), [20(pad32) x 256] @ [256->128] ---
  {
    int n0 = wv * 32 + r16, n1 = n0 + 16;
    int arow0 = r16, arow1 = 16 + (r16 & 3);   // mt=1 aliases rows 16-19
    f32x4 acc[2][2] = {};
    for (int kt = 0; kt < 8; ++kt) {
      long w0 = ((long)(kt * 128 + n0)) * 32 + khh * 8;
      long w1 = ((long)(kt * 128 + n1)) * 32 + khh * 8;
      short8v b0h = *(const short8v*)(WAH + w0);
      short8v b0l = *(const short8v*)(WAL + w0);
      short8v b1h = *(const short8v*)(WAH + w1);
      short8v b1l = *(const short8v*)(WAL + w1);
#pragma unroll
      for (int mt = 0; mt < 2; ++mt) {
        int ar = (mt == 0) ? arow0 : arow1;
        short8v ahi = *(const short8v*)&XbH[ar][kt * 32 + khh * 8];
        short8v alo = *(const short8v*)&XbL[ar][kt * 32 + khh * 8];
        acc[mt][0] = __builtin_amdgcn_mfma_f32_16x16x32_bf16(ahi, b0h, acc[mt][0], 0, 0, 0);
        acc[mt][0] = __builtin_amdgcn_mfma_f32_16x16x32_bf16(ahi, b0l, acc[mt][0], 0, 0, 0);
        acc[mt][0] = __builtin_amdgcn_mfma_f32_16x16x32_bf16(alo, b0h, acc[mt][0], 0, 0, 0);
        acc[mt][1] = __builtin_amdgcn_mfma_f32_16x16x32_bf16(ahi, b1h, acc[mt][1], 0, 0, 0);
        acc[mt][1] = __builtin_amdgcn_mfma_f32_16x16x32_bf16(ahi, b1l, acc[mt][1], 0, 0, 0);
        acc[mt][1] = __builtin_amdgcn_mfma_f32_16x16x32_bf16(alo, b1h, acc[mt][1], 0, 0, 0);
      }
    }
    float bc0 = ws[OFF_BANC + n0], bc1 = ws[OFF_BANC + n1];
#pragma unroll
    for (int mt = 0; mt < 2; ++mt)
#pragma unroll
      for (int j = 0; j < 4; ++j) {
        int r = mt * 16 + khh * 4 + j;
        if (r < 20) {
          unsigned short hi, lo;
          float h0 = tanhf(acc[mt][0][j] + bc0);
          splitbf(h0, hi, lo);
          Hhi[r][n0] = hi; Hlo[r][n0] = lo;
          float h1v = tanhf(acc[mt][1][j] + bc1);
          splitbf(h1v, hi, lo);
          Hhi[r][n1] = hi; Hlo[r][n1] = lo;
        }
      }
  }
  __syncthreads();

  // --- Stage C: logits = elu(H@Waw1^T+b1)@w2 + b2, [20(pad32)x128]@[128->128] ---
  {
    int n0 = wv * 32 + r16, n1 = n0 + 16;
    int hrow0 = r16, hrow1 = 16 + (r16 & 3);
    float b10 = ws[OFF_BAW1 + n0], b11 = ws[OFF_BAW1 + n1];
    float w20 = ws[OFF_WAW2 + n0], w21 = ws[OFF_WAW2 + n1];
    f32x4 ac[2][2] = {};
    for (int kt = 0; kt < 4; ++kt) {
      long w0 = ((long)(kt * 128 + n0)) * 32 + khh * 8;
      long w1 = ((long)(kt * 128 + n1)) * 32 + khh * 8;
      short8v b0h = *(const short8v*)(W1H + w0);
      short8v b0l = *(const short8v*)(W1L + w0);
      short8v b1h = *(const short8v*)(W1H + w1);
      short8v b1l = *(const short8v*)(W1L + w1);
#pragma unroll
      for (int mt = 0; mt < 2; ++mt) {
        int hr = (mt == 0) ? hrow0 : hrow1;
        short8v ahi = *(const short8v*)&Hhi[hr][kt * 32 + khh * 8];
        short8v alo = *(const short8v*)&Hlo[hr][kt * 32 + khh * 8];
        ac[mt][0] = __builtin_amdgcn_mfma_f32_16x16x32_bf16(ahi, b0h, ac[mt][0], 0, 0, 0);
        ac[mt][0] = __builtin_amdgcn_mfma_f32_16x16x32_bf16(ahi, b0l, ac[mt][0], 0, 0, 0);
        ac[mt][0] = __builtin_amdgcn_mfma_f32_16x16x32_bf16(alo, b0h, ac[mt][0], 0, 0, 0);
        ac[mt][1] = __builtin_amdgcn_mfma_f32_16x16x32_bf16(ahi, b1h, ac[mt][1], 0, 0, 0);
        ac[mt][1] = __builtin_amdgcn_mfma_f32_16x16x32_bf16(ahi, b1l, ac[mt][1], 0, 0, 0);
        ac[mt][1] = __builtin_amdgcn_mfma_f32_16x16x32_bf16(alo, b1h, ac[mt][1], 0, 0, 0);
      }
    }
#pragma unroll
    for (int mt = 0; mt < 2; ++mt)
#pragma unroll
      for (int j = 0; j < 4; ++j) {
        float v = eluf(ac[mt][0][j] + b10) * w20 + eluf(ac[mt][1][j] + b11) * w21;
        v += __shfl_xor(v, 1);
        v += __shfl_xor(v, 2);
        v += __shfl_xor(v, 4);
        v += __shfl_xor(v, 8);
        int r = mt * 16 + khh * 4 + j;
        if (r16 == 0 && r < 20) LGp[wv][r] = v;
      }
  }
  __syncthreads();

  // --- Stage D: softmax over 20 anchors + weighted sum (128 threads) ---
  if (tid < 128) {
    float bw2 = ws[OFF_BAW2];
    float e[20], mx = -1e30f;
#pragma unroll
    for (int a = 0; a < 20; ++a) {
      e[a] = LGp[0][a] + LGp[1][a] + LGp[2][a] + LGp[3][a] + bw2;
      mx = fmaxf(mx, e[a]);
    }
    float s = 0.f;
#pragma unroll
    for (int a = 0; a < 20; ++a) { e[a] = expf(e[a] - mx); s += e[a]; }
    float inv = 1.0f / s;
    float o = 0.f;
#pragma unroll
    for (int a = 0; a < 20; ++a)
      o += e[a] * (bfh(Hhi[a][tid]) + bfh(Hlo[a][tid]));
    float* AE = ws + OFF_AE;
    AE[(long)blockIdx.x * 128 + tid] = o * inv;
  }
}

// ---- K5: final MLP --------------------------------------------------------
__global__ __launch_bounds__(256) void k_mlp(float* ws) {
  __shared__ __align__(16) float xt[16][256];
  __shared__ __align__(16) float h1[16][128];
  int tid = threadIdx.x;
  long r0 = (long)blockIdx.x * 16;
  const float* NE = ws + OFF_NE;
  const float* AE = ws + OFF_AE;
  for (int x = tid; x < 16 * 256; x += 256) {
    int c = x >> 8, k = x & 255;
    xt[c][k] = (k < 128) ? NE[(r0 + c) * 128 + k] : AE[(r0 + c) * 128 + (k - 128)];
  }
  __syncthreads();
  int j = tid & 127, half = tid >> 7;
  const float4* W1 = (const float4*)(ws + OFF_WM1P);
  float acc[8];
#pragma unroll
  for (int c = 0; c < 8; c++) acc[c] = 0.f;
  for (int k4 = 0; k4 < 64; k4++) {
    float4 w = W1[k4 * 128 + j];
#pragma unroll
    for (int c = 0; c < 8; c++) {
      const float4 xv = *(const float4*)&xt[half * 8 + c][k4 * 4];
      acc[c] += w.x * xv.x + w.y * xv.y + w.z * xv.z + w.w * xv.w;
    }
  }
  float b1 = ws[OFF_BM1 + j];
#pragma unroll
  for (int c = 0; c < 8; c++) h1[half * 8 + c][j] = eluf(acc[c] + b1);
  __syncthreads();
  const float4* W2 = (const float4*)(ws + OFF_WM2P);
  float a2[8];
#pragma unroll
  for (int c = 0; c < 8; c++) a2[c] = 0.f;
  for (int k4 = 0; k4 < 32; k4++) {
    float4 w = W2[k4 * 128 + j];
#pragma unroll
    for (int c = 0; c < 8; c++) {
      const float4 xv = *(const float4*)&h1[half * 8 + c][k4 * 4];
      a2[c] += w.x * xv.x + w.y * xv.y + w.z * xv.z + w.w * xv.w;
    }
  }
  float b2 = ws[OFF_BM2 + j];
  float* MO = ws + OFF_MO;
#pragma unroll
  for (int c = 0; c < 8; c++) MO[(r0 + half * 8 + c) * 128 + j] = eluf(a2[c] + b2);
}

// ---- K6: user mean + scores ----------------------------------------------
__global__ __launch_bounds__(128) void k_score(const float* ws, void* out) {
  const int bf = ((const int*)ws)[0];
  int b = blockIdx.x;
  int d = threadIdx.x;
  const float* MO = ws + OFF_MO;
  float u = 0.f;
  for (int t = 0; t < UC_; t++) u += MO[(long)(NCAND + b * UC_ + t) * 128 + d];
  u *= (1.0f / UC_);
  __shared__ float red[2];
  for (int s = 0; s < S_; s++) {
    float p = MO[(long)(b * S_ + s) * 128 + d] * u;
#pragma unroll
    for (int o = 32; o > 0; o >>= 1) p += __shfl_down(p, o, 64);
    if ((d & 63) == 0) red[d >> 6] = p;
    __syncthreads();
    if (d == 0) {
      float v = red[0] + red[1];
      if (bf)
        ((__hip_bfloat16*)out)[b * S_ + s] = __float2bfloat16(v);
      else
        ((float*)out)[b * S_ + s] = v;
    }
    __syncthreads();
  }
}

extern "C" void kernel_launch(void* const* d_in, const int* in_sizes, int n_in,
                              void* d_out, int out_size, void* d_ws, size_t ws_size,
                              hipStream_t stream) {
  (void)in_sizes; (void)n_in; (void)out_size; (void)ws_size;
  const void* titles = d_in[0];
  const void* ent    = d_in[1];
  const void* rel    = d_in[2];
  const void* Wnc1 = d_in[3];  const void* bnc1 = d_in[4];
  const void* Wnc2 = d_in[5];  const void* bnc2 = d_in[6];
  const void* Wanc = d_in[7];  const void* banc = d_in[8];
  const void* Waw1 = d_in[9];  const void* baw1 = d_in[10];
  const void* Waw2 = d_in[11]; const void* baw2 = d_in[12];
  const void* Wm1  = d_in[13]; const void* bm1  = d_in[14];
  const void* Wm2  = d_in[15]; const void* bm2  = d_in[16];
  const int* cand  = (const int*)d_in[17];
  const int* clk   = (const int*)d_in[18];
  const int* canda = (const int*)d_in[19];
  const int* clka  = (const int*)d_in[20];
  const int* eadj  = (const int*)d_in[21];
  const int* radj  = (const int*)d_in[22];
  float* ws = (float*)d_ws;

  k_prep<<<256, 256, 0, stream>>>(Wnc1, bnc1, Wnc2, bnc2, Wanc, banc, Waw1, baw1,
                                  Waw2, baw2, Wm1, bm1, Wm2, bm2, rel, ent, ws);
  k_news<<<NNEWS / 8, 128, 0, stream>>>(titles, cand, clk, ws);
  k_anchor<<<NNEWS, 256, 0, stream>>>(ent, canda, clka, eadj, radj, ws);
  k_mlp<<<NNEWS / 16, 256, 0, stream>>>(ws);
  k_score<<<B_, 128, 0, stream>>>(ws, d_out);
}